// Round 1
// baseline (477.201 us; speedup 1.0000x reference)
//
#include <hip/hip_runtime.h>
#include <hip/hip_bf16.h>

// MultiHeadAttention fused forward for MI355X (gfx950).
// B=2, S=2048, D=1024, H=16, DH=64. Outputs: out [B,S,D] fp32, attn [B,H,S,S] fp32.
static constexpr int cB = 2, cS = 2048, cD = 1024, cH = 16, cDH = 64;

typedef __attribute__((ext_vector_type(4))) float f32x4;
typedef __attribute__((ext_vector_type(8))) short s16x8;
typedef unsigned long long u64;
typedef unsigned short u16;

__device__ inline f32x4 mfma16(s16x8 a, s16x8 b, f32x4 c) {
  return __builtin_amdgcn_mfma_f32_16x16x32_bf16(a, b, c, 0, 0, 0);
}

// fp32 -> bf16 round-to-nearest-even (bit manipulation; inputs are finite)
__device__ inline u16 f2bf(float x) {
  unsigned u = __float_as_uint(x);
  u += 0x7FFFu + ((u >> 16) & 1u);
  return (u16)(u >> 16);
}

// Load one MFMA operand fragment (8 bf16) from an LDS row.
// k positions: off..off+3 and off+16..off+19 where off = c*32 + 4*g.
// A and B fragments always use the SAME (g,e)->k map, so the contraction is
// invariant to the true intra-lane k ordering of the hardware.
__device__ inline s16x8 frag2(const u16* rowbase, int off) {
  union { s16x8 v; u64 q[2]; } f;
  f.q[0] = *(const u64*)(rowbase + off);
  f.q[1] = *(const u64*)(rowbase + off + 16);
  return f.v;
}

__device__ inline f32x4 zero4() { f32x4 z; z[0] = z[1] = z[2] = z[3] = 0.f; return z; }

#define LDT 72  // padded LDS row stride (bf16 elems); 144B, multiple of 16B

// ---------------- W transpose + bf16 convert: W[k][n] fp32 -> Wt[n][k] bf16 ----
__global__ __launch_bounds__(256) void wt_kernel(const float* __restrict__ W,
                                                 u16* __restrict__ Wt) {
  __shared__ float tile[32][33];
  int tx = threadIdx.x, ty = threadIdx.y;
  int r0 = blockIdx.y * 32, c0 = blockIdx.x * 32;
  for (int i = ty; i < 32; i += 8)
    tile[i][tx] = W[(size_t)(r0 + i) * cD + c0 + tx];
  __syncthreads();
  for (int i = ty; i < 32; i += 8)
    Wt[(size_t)(c0 + i) * cD + r0 + tx] = f2bf(tile[tx][i]);
}

// ---------------- mask nonzero bitmap: flag per (b, 64-row qtile, 64-col ktile) --
__global__ __launch_bounds__(256) void maskflag_kernel(const float* __restrict__ mask,
                                                       unsigned char* __restrict__ flags) {
  int blk = blockIdx.x;                       // b*1024 + qt*32 + kt
  int b = blk >> 10, qt = (blk >> 5) & 31, kt = blk & 31;
  int t = threadIdx.x;
  int r = t >> 2, c0 = (t & 3) * 16;
  const float4* p = (const float4*)(mask + ((size_t)b * cS + qt * 64 + r) * cS + kt * 64 + c0);
  int any = 0;
  for (int j = 0; j < 4; ++j) {
    float4 v = p[j];
    any |= (v.x != 0.f) | (v.y != 0.f) | (v.z != 0.f) | (v.w != 0.f);
  }
  __shared__ int sred;
  if (t == 0) sred = 0;
  __syncthreads();
  if (any) atomicOr(&sred, 1);
  __syncthreads();
  if (t == 0) flags[blk] = (unsigned char)sred;
}

// ---------------- projection GEMM: out = (X @ W + bias) * scale, bf16 out ------
// X fp32 [4096][1024], Wt bf16 [n][k]. BM=128, BN=64, BK=64, 256 thr (4 waves).
// vt_mode==0: out[((b*H+h)*S+s)*DH+d]  (Q/K layout)
// vt_mode==1: out[((b*H+h)*DH+d)*S+s]  (V transposed layout)
__global__ __launch_bounds__(256) void proj_gemm(const float* __restrict__ X,
                                                 const u16* __restrict__ Wt,
                                                 const float* __restrict__ bias,
                                                 u16* __restrict__ out,
                                                 float scale, int vt_mode) {
  __shared__ __attribute__((aligned(16))) u16 Al[128][LDT];
  __shared__ __attribute__((aligned(16))) u16 Bl[64][LDT];
  int t = threadIdx.x;
  int w = t >> 6, l = t & 63, g = l >> 4, li = l & 15;
  int bm = blockIdx.x & 31, bn = blockIdx.x >> 5;
  int m0 = bm * 128, n0 = bn * 64;

  f32x4 acc[2][4];
  for (int i = 0; i < 2; ++i)
    for (int j = 0; j < 4; ++j) acc[i][j] = zero4();

  int ar = t >> 1, ak0 = (t & 1) * 32;   // A staging: 32 fp32 per thread
  int bnr = t >> 2, bk0 = (t & 3) * 16;  // B staging: 16 bf16 per thread

  for (int kk = 0; kk < cD; kk += 64) {
    const float* asrc = X + (size_t)(m0 + ar) * cD + kk + ak0;
    for (int j = 0; j < 4; ++j) {
      float4 x0 = ((const float4*)asrc)[2 * j];
      float4 x1 = ((const float4*)asrc)[2 * j + 1];
      union { s16x8 v; u16 h[8]; } s;
      s.h[0] = f2bf(x0.x); s.h[1] = f2bf(x0.y); s.h[2] = f2bf(x0.z); s.h[3] = f2bf(x0.w);
      s.h[4] = f2bf(x1.x); s.h[5] = f2bf(x1.y); s.h[6] = f2bf(x1.z); s.h[7] = f2bf(x1.w);
      *(s16x8*)&Al[ar][ak0 + 8 * j] = s.v;
    }
    const u16* bsrc = Wt + (size_t)(n0 + bnr) * cD + kk + bk0;
    *(s16x8*)&Bl[bnr][bk0]     = *(const s16x8*)bsrc;
    *(s16x8*)&Bl[bnr][bk0 + 8] = *(const s16x8*)(bsrc + 8);
    __syncthreads();
    for (int c = 0; c < 2; ++c) {
      s16x8 a0 = frag2(&Al[w * 32 + li][0],      c * 32 + 4 * g);
      s16x8 a1 = frag2(&Al[w * 32 + 16 + li][0], c * 32 + 4 * g);
      for (int ni = 0; ni < 4; ++ni) {
        s16x8 b = frag2(&Bl[ni * 16 + li][0], c * 32 + 4 * g);
        acc[0][ni] = mfma16(a0, b, acc[0][ni]);
        acc[1][ni] = mfma16(a1, b, acc[1][ni]);
      }
    }
    __syncthreads();
  }

  for (int ni = 0; ni < 4; ++ni) {
    int n = n0 + ni * 16 + li;
    float bv = bias[n];
    int h = n >> 6, d = n & 63;
    for (int mi = 0; mi < 2; ++mi) {
      for (int r = 0; r < 4; ++r) {
        int m = m0 + w * 32 + mi * 16 + g * 4 + r;
        float val = (acc[mi][ni][r] + bv) * scale;
        int b = m >> 11, s = m & 2047;
        size_t idx;
        if (vt_mode) idx = ((size_t)(b * cH + h) * cDH + d) * cS + s;
        else         idx = ((size_t)(b * cH + h) * cS + s) * cDH + d;
        out[idx] = f2bf(val);
      }
    }
  }
}

// ---------------- output GEMM: out = Xc @ Wo + bo, fp32 out --------------------
__global__ __launch_bounds__(256) void out_gemm(const u16* __restrict__ Xc,
                                                const u16* __restrict__ Wt,
                                                const float* __restrict__ bias,
                                                float* __restrict__ out) {
  __shared__ __attribute__((aligned(16))) u16 Al[128][LDT];
  __shared__ __attribute__((aligned(16))) u16 Bl[64][LDT];
  int t = threadIdx.x;
  int w = t >> 6, l = t & 63, g = l >> 4, li = l & 15;
  int bm = blockIdx.x & 31, bn = blockIdx.x >> 5;
  int m0 = bm * 128, n0 = bn * 64;

  f32x4 acc[2][4];
  for (int i = 0; i < 2; ++i)
    for (int j = 0; j < 4; ++j) acc[i][j] = zero4();

  int ar = t >> 1, ak0 = (t & 1) * 32;
  int bnr = t >> 2, bk0 = (t & 3) * 16;

  for (int kk = 0; kk < cD; kk += 64) {
    const u16* asrc = Xc + (size_t)(m0 + ar) * cD + kk + ak0;
    for (int j = 0; j < 4; ++j)
      *(s16x8*)&Al[ar][ak0 + 8 * j] = *(const s16x8*)(asrc + 8 * j);
    const u16* bsrc = Wt + (size_t)(n0 + bnr) * cD + kk + bk0;
    *(s16x8*)&Bl[bnr][bk0]     = *(const s16x8*)bsrc;
    *(s16x8*)&Bl[bnr][bk0 + 8] = *(const s16x8*)(bsrc + 8);
    __syncthreads();
    for (int c = 0; c < 2; ++c) {
      s16x8 a0 = frag2(&Al[w * 32 + li][0],      c * 32 + 4 * g);
      s16x8 a1 = frag2(&Al[w * 32 + 16 + li][0], c * 32 + 4 * g);
      for (int ni = 0; ni < 4; ++ni) {
        s16x8 b = frag2(&Bl[ni * 16 + li][0], c * 32 + 4 * g);
        acc[0][ni] = mfma16(a0, b, acc[0][ni]);
        acc[1][ni] = mfma16(a1, b, acc[1][ni]);
      }
    }
    __syncthreads();
  }

  for (int ni = 0; ni < 4; ++ni) {
    int n = n0 + ni * 16 + li;
    float bv = bias[n];
    for (int mi = 0; mi < 2; ++mi)
      for (int r = 0; r < 4; ++r) {
        int m = m0 + w * 32 + mi * 16 + g * 4 + r;
        out[(size_t)m * cD + n] = acc[mi][ni][r] + bv;
      }
  }
}

// ---------------- fused attention ---------------------------------------------
// Grid: B*H*(S/64) = 1024 blocks, 256 threads (4 waves, 16 q-rows each).
// Pass A: softmax denominators (raw exp; logits are O(10), no overflow risk).
// Pass B: recompute QK^T, write normalized attn fp32, PV via per-wave LDS bounce.
__global__ __launch_bounds__(256) void attn_kernel(const u16* __restrict__ Q,
                                                   const u16* __restrict__ K,
                                                   const u16* __restrict__ Vt,
                                                   const float* __restrict__ mask,
                                                   const unsigned char* __restrict__ flags,
                                                   float* __restrict__ attn,
                                                   u16* __restrict__ ctx) {
  __shared__ __attribute__((aligned(16))) u16 Kl[64][LDT];
  __shared__ __attribute__((aligned(16))) u16 Vl[64][LDT];
  __shared__ __attribute__((aligned(16))) u16 Pl[4][16][LDT];
  int t = threadIdx.x;
  int w = t >> 6, l = t & 63, g = l >> 4, li = l & 15;
  int blk = blockIdx.x;
  int bh = blk >> 5, qt = blk & 31;
  int b = bh >> 4, h = bh & 15;
  int qbase = qt * 64;
  const u16* Qh = Q + (size_t)bh * cS * cDH;
  const u16* Kh = K + (size_t)bh * cS * cDH;
  const u16* Vh = Vt + (size_t)bh * cDH * cS;
  const unsigned char* fl = flags + (b << 10) + qt * 32;

  // Q fragments, held in registers for both passes (Q pre-scaled by 1/8)
  s16x8 qf[2];
  {
    const u16* qp = Qh + (size_t)(qbase + w * 16 + li) * cDH;
    qf[0] = frag2(qp, 4 * g);
    qf[1] = frag2(qp, 32 + 4 * g);
  }
  int sr = t >> 2, sc0 = (t & 3) * 16;  // staging map: 64 rows x 64 cols bf16

  // ---- Pass A: row sums of exp(logits) ----
  float rs[4] = {0.f, 0.f, 0.f, 0.f};
  for (int kt = 0; kt < 32; ++kt) {
    const u16* ksrc = Kh + (size_t)(kt * 64 + sr) * cDH + sc0;
    *(s16x8*)&Kl[sr][sc0]     = *(const s16x8*)ksrc;
    *(s16x8*)&Kl[sr][sc0 + 8] = *(const s16x8*)(ksrc + 8);
    __syncthreads();
    f32x4 acc[4];
    for (int nt = 0; nt < 4; ++nt) acc[nt] = zero4();
    for (int c = 0; c < 2; ++c)
      for (int nt = 0; nt < 4; ++nt) {
        s16x8 bfr = frag2(&Kl[nt * 16 + li][0], c * 32 + 4 * g);
        acc[nt] = mfma16(qf[c], bfr, acc[nt]);
      }
    bool um = fl[kt] != 0;
    for (int nt = 0; nt < 4; ++nt)
      for (int r = 0; r < 4; ++r) {
        float lv = acc[nt][r];
        if (um) {
          int qg = qbase + w * 16 + g * 4 + r;
          int kg = kt * 64 + nt * 16 + li;
          lv += mask[((size_t)b * cS + qg) * cS + kg] * -1e9f;
        }
        rs[r] += __expf(lv);
      }
    __syncthreads();
  }
  // butterfly across the 16 lanes holding one row's columns
  for (int r = 0; r < 4; ++r) {
    for (int msk = 1; msk < 16; msk <<= 1) rs[r] += __shfl_xor(rs[r], msk, 64);
    rs[r] = 1.f / rs[r];  // now the inverse denominator
  }

  // ---- Pass B: attn write + PV ----
  f32x4 cacc[4];
  for (int dt = 0; dt < 4; ++dt) cacc[dt] = zero4();
  float* attn_base = attn + (size_t)bh * cS * cS;
  for (int kt = 0; kt < 32; ++kt) {
    const u16* ksrc = Kh + (size_t)(kt * 64 + sr) * cDH + sc0;
    *(s16x8*)&Kl[sr][sc0]     = *(const s16x8*)ksrc;
    *(s16x8*)&Kl[sr][sc0 + 8] = *(const s16x8*)(ksrc + 8);
    const u16* vsrc = Vh + (size_t)sr * cS + kt * 64 + sc0;
    *(s16x8*)&Vl[sr][sc0]     = *(const s16x8*)vsrc;
    *(s16x8*)&Vl[sr][sc0 + 8] = *(const s16x8*)(vsrc + 8);
    __syncthreads();
    f32x4 acc[4];
    for (int nt = 0; nt < 4; ++nt) acc[nt] = zero4();
    for (int c = 0; c < 2; ++c)
      for (int nt = 0; nt < 4; ++nt) {
        s16x8 bfr = frag2(&Kl[nt * 16 + li][0], c * 32 + 4 * g);
        acc[nt] = mfma16(qf[c], bfr, acc[nt]);
      }
    bool um = fl[kt] != 0;
    for (int nt = 0; nt < 4; ++nt) {
      int kg = kt * 64 + nt * 16 + li;
      for (int r = 0; r < 4; ++r) {
        float lv = acc[nt][r];
        int qg = qbase + w * 16 + g * 4 + r;
        if (um) lv += mask[((size_t)b * cS + qg) * cS + kg] * -1e9f;
        float p = __expf(lv) * rs[r];
        attn_base[(size_t)qg * cS + kg] = p;
        Pl[w][g * 4 + r][nt * 16 + li] = f2bf(p);
      }
    }
    // PV: A = P (per-wave LDS, same-wave RAW handled by compiler lgkmcnt)
    for (int c = 0; c < 2; ++c) {
      s16x8 pa = frag2(&Pl[w][li][0], c * 32 + 4 * g);
      for (int dt = 0; dt < 4; ++dt) {
        s16x8 bv2 = frag2(&Vl[dt * 16 + li][0], c * 32 + 4 * g);
        cacc[dt] = mfma16(pa, bv2, cacc[dt]);
      }
    }
    __syncthreads();
  }

  // ctx -> concat layout [b*S+s][h*64+d] bf16 for the output GEMM
  for (int dt = 0; dt < 4; ++dt)
    for (int r = 0; r < 4; ++r) {
      int s = qbase + w * 16 + g * 4 + r;
      int d = dt * 16 + li;
      ctx[((size_t)(b * cS + s)) * cD + h * 64 + d] = f2bf(cacc[dt][r]);
    }
}

// ---------------- host launch --------------------------------------------------
extern "C" void kernel_launch(void* const* d_in, const int* in_sizes, int n_in,
                              void* d_out, int out_size, void* d_ws, size_t ws_size,
                              hipStream_t stream) {
  const float* q_in = (const float*)d_in[0];
  const float* k_in = (const float*)d_in[1];
  const float* v_in = (const float*)d_in[2];
  const float* mask = (const float*)d_in[3];
  const float* Wq = (const float*)d_in[4];
  const float* bq = (const float*)d_in[5];
  const float* Wk = (const float*)d_in[6];
  const float* bk = (const float*)d_in[7];
  const float* Wv = (const float*)d_in[8];
  const float* bv = (const float*)d_in[9];
  const float* Wo = (const float*)d_in[10];
  const float* bo = (const float*)d_in[11];

  float* out = (float*)d_out;                       // [B,S,D]
  float* attn = out + (size_t)cB * cS * cD;         // [B,H,S,S]

  // workspace layout (bf16 = 2B): 4 W^T (8MB) + Q + K + Vt + ctx (8MB ea) + flags
  const size_t MATB = (size_t)cB * cS * cD * 2;     // 8,388,608 B
  const size_t WB = (size_t)cD * cD * 2;            // 2,097,152 B
  char* ws = (char*)d_ws;
  u16* WqT = (u16*)(ws);
  u16* WkT = (u16*)(ws + WB);
  u16* WvT = (u16*)(ws + 2 * WB);
  u16* WoT = (u16*)(ws + 3 * WB);
  u16* wsQ  = (u16*)(ws + 4 * WB);
  u16* wsK  = (u16*)(ws + 4 * WB + MATB);
  u16* wsVt = (u16*)(ws + 4 * WB + 2 * MATB);
  u16* wsC  = (u16*)(ws + 4 * WB + 3 * MATB);
  unsigned char* flags = (unsigned char*)(ws + 4 * WB + 4 * MATB);
  const size_t REQUIRED = 4 * WB + 4 * MATB + 2048;
  if (ws_size < REQUIRED) return;  // loud failure (validation will catch)

  dim3 tb(32, 8);
  wt_kernel<<<dim3(32, 32), tb, 0, stream>>>(Wq, WqT);
  wt_kernel<<<dim3(32, 32), tb, 0, stream>>>(Wk, WkT);
  wt_kernel<<<dim3(32, 32), tb, 0, stream>>>(Wv, WvT);
  wt_kernel<<<dim3(32, 32), tb, 0, stream>>>(Wo, WoT);
  maskflag_kernel<<<2048, 256, 0, stream>>>(mask, flags);

  proj_gemm<<<512, 256, 0, stream>>>(q_in, WqT, bq, wsQ, 0.125f, 0);  // Q, pre-scaled 1/sqrt(DH)
  proj_gemm<<<512, 256, 0, stream>>>(k_in, WkT, bk, wsK, 1.0f, 0);
  proj_gemm<<<512, 256, 0, stream>>>(v_in, WvT, bv, wsVt, 1.0f, 1);   // V transposed

  attn_kernel<<<1024, 256, 0, stream>>>(wsQ, wsK, wsVt, mask, flags, attn, wsC);

  out_gemm<<<512, 256, 0, stream>>>(wsC, WoT, bo, out);
}

// Round 2
// 404.888 us; speedup vs baseline: 1.1786x; 1.1786x over previous
//
#include <hip/hip_runtime.h>
#include <hip/hip_bf16.h>

// MultiHeadAttention fused forward for MI355X (gfx950).
// B=2, S=2048, D=1024, H=16, DH=64. Outputs: out [B,S,D] fp32, attn [B,H,S,S] fp32.
static constexpr int cB = 2, cS = 2048, cD = 1024, cH = 16, cDH = 64;

typedef __attribute__((ext_vector_type(4))) float f32x4;
typedef __attribute__((ext_vector_type(8))) short s16x8;
typedef unsigned long long u64;
typedef unsigned short u16;

__device__ inline f32x4 mfma16(s16x8 a, s16x8 b, f32x4 c) {
  return __builtin_amdgcn_mfma_f32_16x16x32_bf16(a, b, c, 0, 0, 0);
}

// fp32 -> bf16 round-to-nearest-even
__device__ inline u16 f2bf(float x) {
  unsigned u = __float_as_uint(x);
  u += 0x7FFFu + ((u >> 16) & 1u);
  return (u16)(u >> 16);
}

__device__ inline f32x4 zero4() { f32x4 z; z[0] = z[1] = z[2] = z[3] = 0.f; return z; }

// global -> LDS direct copy, 16 B per lane. dst is the wave-uniform base; HW
// adds lane*16. src is per-lane.
__device__ inline void gload16(const void* src, void* dst) {
  __builtin_amdgcn_global_load_lds((const __attribute__((address_space(1))) void*)src,
                                   (__attribute__((address_space(3))) void*)dst, 16, 0, 0);
}

#define LDT 72  // padded row stride for the P bounce buffer (bf16 elems)

// Fragment k-map (A and B identical, bijective per 16-lane group):
//   lane (g = l>>4), MFMA instance c: k = c*32 + g*8 .. +7  (8 contiguous bf16)
// Tiles in LDS are [rows][8 chunks of 16B] with chunk XOR-swizzle: the 16B chunk
// holding global chunk q of row r sits at LDS chunk q ^ (r&7). Staged either by
// inverse-swizzled global_load_lds source or swizzled ds_write (rule: both sides).

// ---------------- W transpose + bf16 convert: W[k][n] fp32 -> Wt[n][k] bf16 ----
__global__ __launch_bounds__(256) void wt_kernel(const float* __restrict__ W,
                                                 u16* __restrict__ Wt) {
  __shared__ float tile[32][33];
  int tx = threadIdx.x, ty = threadIdx.y;
  int r0 = blockIdx.y * 32, c0 = blockIdx.x * 32;
  for (int i = ty; i < 32; i += 8)
    tile[i][tx] = W[(size_t)(r0 + i) * cD + c0 + tx];
  __syncthreads();
  for (int i = ty; i < 32; i += 8)
    Wt[(size_t)(c0 + i) * cD + r0 + tx] = f2bf(tile[tx][i]);
}

// ---------------- mask nonzero bitmap: flag per (b, 64-row qtile, 64-col ktile) --
__global__ __launch_bounds__(256) void maskflag_kernel(const float* __restrict__ mask,
                                                       unsigned char* __restrict__ flags) {
  int blk = blockIdx.x;                       // b*1024 + qt*32 + kt
  int b = blk >> 10, qt = (blk >> 5) & 31, kt = blk & 31;
  int t = threadIdx.x;
  int r = t >> 2, c0 = (t & 3) * 16;
  const float4* p = (const float4*)(mask + ((size_t)b * cS + qt * 64 + r) * cS + kt * 64 + c0);
  int any = 0;
  for (int j = 0; j < 4; ++j) {
    float4 v = p[j];
    any |= (v.x != 0.f) | (v.y != 0.f) | (v.z != 0.f) | (v.w != 0.f);
  }
  __shared__ int sred;
  if (t == 0) sred = 0;
  __syncthreads();
  if (any) atomicOr(&sred, 1);
  __syncthreads();
  if (t == 0) flags[blk] = (unsigned char)sred;
}

// ---------------- 128x128x64 GEMM, 4 waves, 4x4 frags/wave -----------------------
// A: [4096][1024] (fp32 if AFP32, else bf16). Bt: [1024][1024] bf16 row-major (N,K).
// OUTF32: out fp32 [4096][1024] (+bias). else: bf16 out with bias+scale and
// vt_mode layout (0: [bh][s][d], 1: [bh][d][s]).
template<bool AFP32, bool OUTF32>
__global__ __launch_bounds__(256) void gemm128(const void* __restrict__ Ap,
                                               const u16* __restrict__ Bt,
                                               const float* __restrict__ bias,
                                               void* __restrict__ outp,
                                               float scale, int vt_mode) {
  __shared__ __attribute__((aligned(16))) u16 As[128 * 64];
  __shared__ __attribute__((aligned(16))) u16 Bs[128 * 64];
  int t = threadIdx.x;
  int w = t >> 6, l = t & 63, g = l >> 4, li = l & 15;
  int bm = blockIdx.x & 31, bn = blockIdx.x >> 5;
  int m0 = bm * 128, n0 = bn * 128;
  int wr = w >> 1, wc = w & 1;

  f32x4 acc[4][4];
  for (int i = 0; i < 4; ++i)
    for (int j = 0; j < 4; ++j) acc[i][j] = zero4();

  for (int kk = 0; kk < cD; kk += 64) {
    if (AFP32) {
      const float* X = (const float*)Ap;
      int ar = t >> 1, ak0 = (t & 1) * 32;
      const float* asrc = X + (size_t)(m0 + ar) * cD + kk + ak0;
      int sw = ar & 7;
      for (int j = 0; j < 4; ++j) {
        float4 x0 = ((const float4*)asrc)[2 * j];
        float4 x1 = ((const float4*)asrc)[2 * j + 1];
        union { s16x8 v; u16 h[8]; } s;
        s.h[0] = f2bf(x0.x); s.h[1] = f2bf(x0.y); s.h[2] = f2bf(x0.z); s.h[3] = f2bf(x0.w);
        s.h[4] = f2bf(x1.x); s.h[5] = f2bf(x1.y); s.h[6] = f2bf(x1.z); s.h[7] = f2bf(x1.w);
        int chunk = (ak0 >> 3) + j;
        *(s16x8*)&As[ar * 64 + ((chunk ^ sw) * 8)] = s.v;
      }
    } else {
      const u16* X = (const u16*)Ap;
      for (int is = 0; is < 4; ++is) {
        int row = w * 32 + is * 8 + (l >> 3);
        int chunk = l & 7;
        const u16* src = X + (size_t)(m0 + row) * cD + kk + ((chunk ^ (row & 7)) * 8);
        gload16(src, &As[(w * 32 + is * 8) * 64]);
      }
    }
    for (int is = 0; is < 4; ++is) {
      int row = w * 32 + is * 8 + (l >> 3);
      int chunk = l & 7;
      const u16* src = Bt + (size_t)(n0 + row) * cD + kk + ((chunk ^ (row & 7)) * 8);
      gload16(src, &Bs[(w * 32 + is * 8) * 64]);
    }
    __syncthreads();
    for (int c = 0; c < 2; ++c) {
      s16x8 af[4], bf[4];
      for (int mi = 0; mi < 4; ++mi) {
        int r = wr * 64 + mi * 16 + li;
        af[mi] = *(const s16x8*)&As[r * 64 + (((c * 4 + g) ^ (r & 7)) * 8)];
      }
      for (int ni = 0; ni < 4; ++ni) {
        int r = wc * 64 + ni * 16 + li;
        bf[ni] = *(const s16x8*)&Bs[r * 64 + (((c * 4 + g) ^ (r & 7)) * 8)];
      }
      for (int mi = 0; mi < 4; ++mi)
        for (int ni = 0; ni < 4; ++ni)
          acc[mi][ni] = mfma16(af[mi], bf[ni], acc[mi][ni]);
    }
    __syncthreads();
  }

  for (int ni = 0; ni < 4; ++ni) {
    int n = n0 + wc * 64 + ni * 16 + li;
    float bv = bias[n];
    for (int mi = 0; mi < 4; ++mi) {
      for (int r = 0; r < 4; ++r) {
        int m = m0 + wr * 64 + mi * 16 + g * 4 + r;
        float val = acc[mi][ni][r] + bv;
        if (OUTF32) {
          ((float*)outp)[(size_t)m * cD + n] = val;
        } else {
          val *= scale;
          int b = m >> 11, s = m & 2047;
          int h = n >> 6, d = n & 63;
          size_t idx = vt_mode ? ((size_t)(b * cH + h) * cDH + d) * cS + s
                               : ((size_t)(b * cH + h) * cS + s) * cDH + d;
          ((u16*)outp)[idx] = f2bf(val);
        }
      }
    }
  }
}

// ---------------- fused attention ---------------------------------------------
// Grid: B*H*(S/64) = 1024 blocks, 256 threads (4 waves, 16 q-rows each).
// Pass A: softmax denominators (raw exp; logits are O(10), no overflow risk).
// Pass B: recompute QK^T, write normalized attn fp32, PV via per-wave LDS bounce.
__global__ __launch_bounds__(256) void attn_kernel(const u16* __restrict__ Q,
                                                   const u16* __restrict__ K,
                                                   const u16* __restrict__ Vt,
                                                   const float* __restrict__ mask,
                                                   const unsigned char* __restrict__ flags,
                                                   float* __restrict__ attn,
                                                   u16* __restrict__ ctx) {
  __shared__ __attribute__((aligned(16))) u16 Kl[64 * 64];
  __shared__ __attribute__((aligned(16))) u16 Vl[64 * 64];
  __shared__ __attribute__((aligned(16))) u16 Pl[4][16][LDT];
  int t = threadIdx.x;
  int w = t >> 6, l = t & 63, g = l >> 4, li = l & 15;
  int blk = blockIdx.x;
  int bh = blk >> 5, qt = blk & 31;
  int b = bh >> 4;
  int qbase = qt * 64;
  const u16* Qh = Q + (size_t)bh * cS * cDH;
  const u16* Kh = K + (size_t)bh * cS * cDH;
  const u16* Vh = Vt + (size_t)bh * cDH * cS;
  const unsigned char* fl = flags + (b << 10) + qt * 32;

  // Q fragments, held in registers for both passes (Q pre-scaled by 1/8)
  s16x8 qf[2];
  {
    const u16* qp = Qh + (size_t)(qbase + w * 16 + li) * cDH;
    qf[0] = *(const s16x8*)(qp + 8 * g);
    qf[1] = *(const s16x8*)(qp + 32 + 8 * g);
  }
  int srow8 = l >> 3, schunk = l & 7;  // staging lane map (8 rows x 8 chunks per issue)

  // ---- Pass A: row sums of exp(logits) ----
  float rs[4] = {0.f, 0.f, 0.f, 0.f};
  for (int kt = 0; kt < 32; ++kt) {
    for (int is = 0; is < 2; ++is) {
      int row = w * 16 + is * 8 + srow8;
      const u16* src = Kh + (size_t)(kt * 64 + row) * cDH + ((schunk ^ (row & 7)) * 8);
      gload16(src, &Kl[(w * 16 + is * 8) * 64]);
    }
    __syncthreads();
    f32x4 acc[4];
    for (int nt = 0; nt < 4; ++nt) acc[nt] = zero4();
    for (int c = 0; c < 2; ++c)
      for (int nt = 0; nt < 4; ++nt) {
        int r = nt * 16 + li;
        s16x8 bfr = *(const s16x8*)&Kl[r * 64 + (((c * 4 + g) ^ (r & 7)) * 8)];
        acc[nt] = mfma16(qf[c], bfr, acc[nt]);
      }
    bool um = fl[kt] != 0;
    for (int nt = 0; nt < 4; ++nt)
      for (int r = 0; r < 4; ++r) {
        float lv = acc[nt][r];
        if (um) {
          int qg = qbase + w * 16 + g * 4 + r;
          int kg = kt * 64 + nt * 16 + li;
          lv += mask[((size_t)b * cS + qg) * cS + kg] * -1e9f;
        }
        rs[r] += __expf(lv);
      }
    __syncthreads();
  }
  for (int r = 0; r < 4; ++r) {
    for (int msk = 1; msk < 16; msk <<= 1) rs[r] += __shfl_xor(rs[r], msk, 64);
    rs[r] = 1.f / rs[r];  // inverse denominator
  }

  // ---- Pass B: attn write + PV ----
  f32x4 cacc[4];
  for (int dt = 0; dt < 4; ++dt) cacc[dt] = zero4();
  float* attn_base = attn + (size_t)bh * cS * cS;
  for (int kt = 0; kt < 32; ++kt) {
    for (int is = 0; is < 2; ++is) {
      int row = w * 16 + is * 8 + srow8;
      const u16* ksrc = Kh + (size_t)(kt * 64 + row) * cDH + ((schunk ^ (row & 7)) * 8);
      gload16(ksrc, &Kl[(w * 16 + is * 8) * 64]);
      const u16* vsrc = Vh + (size_t)row * cS + kt * 64 + ((schunk ^ (row & 7)) * 8);
      gload16(vsrc, &Vl[(w * 16 + is * 8) * 64]);
    }
    __syncthreads();
    f32x4 acc[4];
    for (int nt = 0; nt < 4; ++nt) acc[nt] = zero4();
    for (int c = 0; c < 2; ++c)
      for (int nt = 0; nt < 4; ++nt) {
        int r = nt * 16 + li;
        s16x8 bfr = *(const s16x8*)&Kl[r * 64 + (((c * 4 + g) ^ (r & 7)) * 8)];
        acc[nt] = mfma16(qf[c], bfr, acc[nt]);
      }
    bool um = fl[kt] != 0;
    for (int nt = 0; nt < 4; ++nt) {
      int kg = kt * 64 + nt * 16 + li;
      for (int r = 0; r < 4; ++r) {
        float lv = acc[nt][r];
        int qg = qbase + w * 16 + g * 4 + r;
        if (um) lv += mask[((size_t)b * cS + qg) * cS + kg] * -1e9f;
        float p = __expf(lv) * rs[r];
        attn_base[(size_t)qg * cS + kg] = p;
        Pl[w][g * 4 + r][nt * 16 + li] = f2bf(p);
      }
    }
    // PV: A = P (per-wave LDS bounce), B = V-tile rows (k), cols d
    for (int c = 0; c < 2; ++c) {
      s16x8 pa = *(const s16x8*)&Pl[w][li][c * 32 + 8 * g];
      for (int dt = 0; dt < 4; ++dt) {
        int r = dt * 16 + li;
        s16x8 bv2 = *(const s16x8*)&Vl[r * 64 + (((c * 4 + g) ^ (r & 7)) * 8)];
        cacc[dt] = mfma16(pa, bv2, cacc[dt]);
      }
    }
    __syncthreads();
  }

  // ctx -> concat layout [b*S+s][h*64+d] bf16 for the output GEMM
  int h = bh & 15;
  for (int dt = 0; dt < 4; ++dt)
    for (int r = 0; r < 4; ++r) {
      int s = qbase + w * 16 + g * 4 + r;
      int d = dt * 16 + li;
      ctx[((size_t)(b * cS + s)) * cD + h * 64 + d] = f2bf(cacc[dt][r]);
    }
}

// ---------------- host launch --------------------------------------------------
extern "C" void kernel_launch(void* const* d_in, const int* in_sizes, int n_in,
                              void* d_out, int out_size, void* d_ws, size_t ws_size,
                              hipStream_t stream) {
  const float* q_in = (const float*)d_in[0];
  const float* k_in = (const float*)d_in[1];
  const float* v_in = (const float*)d_in[2];
  const float* mask = (const float*)d_in[3];
  const float* Wq = (const float*)d_in[4];
  const float* bq = (const float*)d_in[5];
  const float* Wk = (const float*)d_in[6];
  const float* bk = (const float*)d_in[7];
  const float* Wv = (const float*)d_in[8];
  const float* bv = (const float*)d_in[9];
  const float* Wo = (const float*)d_in[10];
  const float* bo = (const float*)d_in[11];

  float* out = (float*)d_out;                       // [B,S,D]
  float* attn = out + (size_t)cB * cS * cD;         // [B,H,S,S]

  // workspace layout (bf16 = 2B): 4 W^T (8MB) + Q + K + Vt + ctx (8MB ea) + flags
  const size_t MATB = (size_t)cB * cS * cD * 2;     // 8,388,608 B
  const size_t WB = (size_t)cD * cD * 2;            // 2,097,152 B
  char* ws = (char*)d_ws;
  u16* WqT = (u16*)(ws);
  u16* WkT = (u16*)(ws + WB);
  u16* WvT = (u16*)(ws + 2 * WB);
  u16* WoT = (u16*)(ws + 3 * WB);
  u16* wsQ  = (u16*)(ws + 4 * WB);
  u16* wsK  = (u16*)(ws + 4 * WB + MATB);
  u16* wsVt = (u16*)(ws + 4 * WB + 2 * MATB);
  u16* wsC  = (u16*)(ws + 4 * WB + 3 * MATB);
  unsigned char* flags = (unsigned char*)(ws + 4 * WB + 4 * MATB);
  const size_t REQUIRED = 4 * WB + 4 * MATB + 2048;
  if (ws_size < REQUIRED) return;  // loud failure (validation will catch)

  dim3 tb(32, 8);
  wt_kernel<<<dim3(32, 32), tb, 0, stream>>>(Wq, WqT);
  wt_kernel<<<dim3(32, 32), tb, 0, stream>>>(Wk, WkT);
  wt_kernel<<<dim3(32, 32), tb, 0, stream>>>(Wv, WvT);
  wt_kernel<<<dim3(32, 32), tb, 0, stream>>>(Wo, WoT);
  maskflag_kernel<<<2048, 256, 0, stream>>>(mask, flags);

  gemm128<true, false><<<256, 256, 0, stream>>>(q_in, WqT, bq, wsQ, 0.125f, 0);
  gemm128<true, false><<<256, 256, 0, stream>>>(k_in, WkT, bk, wsK, 1.0f, 0);
  gemm128<true, false><<<256, 256, 0, stream>>>(v_in, WvT, bv, wsVt, 1.0f, 1);

  attn_kernel<<<1024, 256, 0, stream>>>(wsQ, wsK, wsVt, mask, flags, attn, wsC);

  gemm128<false, true><<<256, 256, 0, stream>>>(wsC, WoT, bo, out, 1.0f, 0);
}